// Round 3
// baseline (372.882 us; speedup 1.0000x reference)
//
#include <hip/hip_runtime.h>
#include <math.h>

#define NSEG   1024
#define DFEAT  128
#define EPS_F  1e-6f

// ps = softplus(ps_raw) with the reference's Threshold(-50) quirk:
// ps = sp if sp < 50 else -50  (never triggers for N(0,1) inputs; kept exact)
__device__ __forceinline__ float softplus_thr(float v) {
    float sp = log1pf(__expf(v));
    return (sp >= 50.0f) ? -50.0f : sp;
}

// Kernel 1: off[j] = lower_bound(batch, j) for j in [0, NSEG]; batch is sorted.
// 1025 independent binary searches, all in flight concurrently (~19 probes each).
__global__ __launch_bounds__(64)
void seg_offsets_kernel(const int* __restrict__ batch, int n_nodes,
                        int* __restrict__ off)
{
    const int j = blockIdx.x * 64 + threadIdx.x;
    if (j > NSEG) return;
    int lo = 0, hi = n_nodes;
    while (lo < hi) {
        const int mid = (lo + hi) >> 1;
        if (batch[mid] < j) lo = mid + 1; else hi = mid;
    }
    off[j] = lo;
}

// Kernel 2: one block per segment. 256 threads = 4 row-groups x 64 lanes.
// Lane l owns feature pair (2l, 2l+1) -> p is lane-constant (ps[0] for the
// first half of D, ps[1] for the second). Branch-free streaming loop ->
// compiler unrolls and keeps loads in flight. Then: LDS reduce (4 partials),
// finalize s^(1/p) * n^(-q0), and the 128-wide dot with W (L2-resident, 64 KB).
__global__ __launch_bounds__(256)
void pool_gemm_kernel(const float* __restrict__ x,
                      const int*   __restrict__ off,
                      const float* __restrict__ ps_raw,
                      const float* __restrict__ qs_raw,
                      const float* __restrict__ W,
                      const float* __restrict__ bias,
                      float* __restrict__ out)
{
    const int b = blockIdx.x;
    const int t = threadIdx.x;
    const int l = t & 63;    // lane within row-group: feature pair (2l, 2l+1)
    const int r = t >> 6;    // row group 0..3

    const int start = off[b];
    const int end   = off[b + 1];

    const float p = softplus_thr(ps_raw[(l < 32) ? 0 : 1]);

    const float2* __restrict__ x2 = (const float2*)x;  // row = 64 float2

    float ax = 0.0f, ay = 0.0f;
#pragma unroll 4
    for (int n = start + r; n < end; n += 4) {
        const float2 v = x2[(size_t)n * 64 + l];
        const float vx = fabsf(v.x) + EPS_F;
        const float vy = fabsf(v.y) + EPS_F;
        // xa^p == exp(p*log(xa)); identical math for both reference branches
        ax += __expf(p * __logf(vx));
        ay += __expf(p * __logf(vy));
    }

    __shared__ float2 part[4][64];
    __shared__ float  g[DFEAT];
    part[r][l] = make_float2(ax, ay);
    __syncthreads();

    if (t < 64) {
        const float2 s0 = part[0][t], s1 = part[1][t];
        const float2 s2 = part[2][t], s3 = part[3][t];
        const float sx = (s0.x + s1.x) + (s2.x + s3.x);
        const float sy = (s0.y + s1.y) + (s2.y + s3.y);
        const float n     = (float)(end - start);
        const float q0    = tanhf(qs_raw[0]);
        const float scale = __expf(-q0 * __logf(n));   // n^(-q0)
        g[2 * t]     = __expf(__logf(sx) / p) * scale; // s^(1/p) * n^(-q0)
        g[2 * t + 1] = __expf(__logf(sy) / p) * scale;
    }
    __syncthreads();

    if (t < DFEAT) {
        const float4* __restrict__ W4 = (const float4*)(W + (size_t)t * DFEAT);
        float acc = bias[t];
#pragma unroll
        for (int jj = 0; jj < DFEAT / 4; ++jj) {
            const float4 w = W4[jj];
            acc += g[4 * jj]     * w.x;
            acc += g[4 * jj + 1] * w.y;
            acc += g[4 * jj + 2] * w.z;
            acc += g[4 * jj + 3] * w.w;
        }
        out[(size_t)b * DFEAT + t] = acc;
    }
}

extern "C" void kernel_launch(void* const* d_in, const int* in_sizes, int n_in,
                              void* d_out, int out_size, void* d_ws, size_t ws_size,
                              hipStream_t stream)
{
    const float* x      = (const float*)d_in[0];
    const int*   batch  = (const int*)  d_in[1];
    const float* ps_raw = (const float*)d_in[2];
    const float* qs_raw = (const float*)d_in[3];
    const float* W      = (const float*)d_in[4];
    const float* bias   = (const float*)d_in[5];
    float*       out    = (float*)d_out;

    const int n_nodes = in_sizes[0] / DFEAT;

    int* off = (int*)d_ws;   // NSEG+1 ints; written before read, no init needed

    seg_offsets_kernel<<<(NSEG + 1 + 63) / 64, 64, 0, stream>>>(batch, n_nodes, off);
    pool_gemm_kernel<<<NSEG, 256, 0, stream>>>(x, off, ps_raw, qs_raw, W, bias, out);
}

// Round 4
// 372.824 us; speedup vs baseline: 1.0002x; 1.0002x over previous
//
#include <hip/hip_runtime.h>
#include <math.h>

#define NSEG   1024
#define DFEAT  128
#define EPS_F  1e-6f

// ps = softplus(ps_raw) with the reference's Threshold(-50) quirk:
// ps = sp if sp < 50 else -50  (never triggers for N(0,1) inputs; kept exact)
__device__ __forceinline__ float softplus_thr(float v) {
    float sp = log1pf(__expf(v));
    return (sp >= 50.0f) ? -50.0f : sp;
}

// Kernel 1: off[j] = lower_bound(batch, j) for j in [0, NSEG]; batch is sorted.
// 1025 independent binary searches, all in flight concurrently (~19 probes each).
__global__ __launch_bounds__(64)
void seg_offsets_kernel(const int* __restrict__ batch, int n_nodes,
                        int* __restrict__ off)
{
    const int j = blockIdx.x * 64 + threadIdx.x;
    if (j > NSEG) return;
    int lo = 0, hi = n_nodes;
    while (lo < hi) {
        const int mid = (lo + hi) >> 1;
        if (batch[mid] < j) lo = mid + 1; else hi = mid;
    }
    off[j] = lo;
}

// Kernel 2: one block per segment, 256 threads.
// Lane t owns float4 column j = t&31 (features 4j..4j+3, so p is lane-constant:
// j<16 -> ps[0], j>=16 -> ps[1]); row-lane rl = t>>5 strides 8 rows.
// Each wave loads 2 rows x 512 B = 1 KB per iteration, branch-free ->
// deep in-flight load queue. Then LDS-reduce 8 partials, finalize
// s^(1/p) * n^(-q0), and the 128x128 dot with W (64 KB, L2-resident).
__global__ __launch_bounds__(256)
void pool_gemm_kernel(const float* __restrict__ x,
                      const int*   __restrict__ off,
                      const float* __restrict__ ps_raw,
                      const float* __restrict__ qs_raw,
                      const float* __restrict__ W,
                      const float* __restrict__ bias,
                      float* __restrict__ out)
{
    const int b  = blockIdx.x;
    const int t  = threadIdx.x;
    const int j  = t & 31;   // float4 column within row
    const int rl = t >> 5;   // row lane 0..7

    const int start = off[b];
    const int end   = off[b + 1];

    const float p = softplus_thr(ps_raw[(j < 16) ? 0 : 1]);

    const float4* __restrict__ x4 = (const float4*)x;  // row = 32 float4

    float ax = 0.0f, ay = 0.0f, az = 0.0f, aw = 0.0f;
#pragma unroll 4
    for (int n = start + rl; n < end; n += 8) {
        const float4 v = x4[(size_t)n * 32 + j];
        // xa^p == exp(p*log(xa)); identical math for both reference branches
        ax += __expf(p * __logf(fabsf(v.x) + EPS_F));
        ay += __expf(p * __logf(fabsf(v.y) + EPS_F));
        az += __expf(p * __logf(fabsf(v.z) + EPS_F));
        aw += __expf(p * __logf(fabsf(v.w) + EPS_F));
    }

    __shared__ float4 part[8][32];
    __shared__ float  g[DFEAT];
    part[rl][j] = make_float4(ax, ay, az, aw);
    __syncthreads();

    if (t < 32) {
        float sx = 0.0f, sy = 0.0f, sz = 0.0f, sw = 0.0f;
#pragma unroll
        for (int r = 0; r < 8; ++r) {
            const float4 v = part[r][t];
            sx += v.x; sy += v.y; sz += v.z; sw += v.w;
        }
        const float n     = (float)(end - start);
        const float q0    = tanhf(qs_raw[0]);
        const float scale = __expf(-q0 * __logf(n));   // n^(-q0)
        const float ip    = 1.0f / p;                  // p is lane-constant here too
        float4 gg;
        gg.x = __expf(__logf(sx) * ip) * scale;        // s^(1/p) * n^(-q0)
        gg.y = __expf(__logf(sy) * ip) * scale;
        gg.z = __expf(__logf(sz) * ip) * scale;
        gg.w = __expf(__logf(sw) * ip) * scale;
        ((float4*)g)[t] = gg;
    }
    __syncthreads();

    if (t < DFEAT) {
        const float4* __restrict__ W4 = (const float4*)(W + (size_t)t * DFEAT);
        float acc = bias[t];
#pragma unroll
        for (int jj = 0; jj < DFEAT / 4; ++jj) {
            const float4 w = W4[jj];
            acc += g[4 * jj]     * w.x;
            acc += g[4 * jj + 1] * w.y;
            acc += g[4 * jj + 2] * w.z;
            acc += g[4 * jj + 3] * w.w;
        }
        out[(size_t)b * DFEAT + t] = acc;
    }
}

extern "C" void kernel_launch(void* const* d_in, const int* in_sizes, int n_in,
                              void* d_out, int out_size, void* d_ws, size_t ws_size,
                              hipStream_t stream)
{
    const float* x      = (const float*)d_in[0];
    const int*   batch  = (const int*)  d_in[1];
    const float* ps_raw = (const float*)d_in[2];
    const float* qs_raw = (const float*)d_in[3];
    const float* W      = (const float*)d_in[4];
    const float* bias   = (const float*)d_in[5];
    float*       out    = (float*)d_out;

    const int n_nodes = in_sizes[0] / DFEAT;

    int* off = (int*)d_ws;   // NSEG+1 ints; written before read, no init needed

    seg_offsets_kernel<<<(NSEG + 1 + 63) / 64, 64, 0, stream>>>(batch, n_nodes, off);
    pool_gemm_kernel<<<NSEG, 256, 0, stream>>>(x, off, ps_raw, qs_raw, W, bias, out);
}